// Round 10
// baseline (378.681 us; speedup 1.0000x reference)
//
#include <hip/hip_runtime.h>
#include <math.h>
#include <stdint.h>

#define N_NODES 50000
#define N_EDGES 800000
#define IN_F 128
#define HID 64

#define NB    782                        // dst buckets of 64 nodes
#define CHUNK 4096
#define NCH   ((N_EDGES + CHUNK - 1) / CHUNK)   // 196
#define TOT   (NB * NCH)                 // 153272
#define SCAN_BLKS ((TOT + 255) / 256)    // 599  (< 1024 for scanB)

#define RB 16000                         // hist bins per range (62.5KB LDS)
#define NR 4                             // 4*16000 >= 50000
#define HP 64                            // slices per range -> 256 blocks

// ---------------------------------------------------------------------------
// src out-degree histogram: LDS-staged, coalesced global flush.
__global__ void hist_src_kernel(const int* __restrict__ src, int* __restrict__ cnt_src) {
    __shared__ int h[RB];
    int r = blockIdx.x / HP;             // range
    int p = blockIdx.x % HP;             // slice
    int t = threadIdx.x;
    for (int i = t; i < RB; i += 256) h[i] = 0;
    __syncthreads();
    int lo = r * RB, hi = lo + RB;
    int base = p * (N_EDGES / HP), lim = base + (N_EDGES / HP);   // 12500 exact
    for (int e = base + t; e < lim; e += 256) {
        int v = src[e];
        if (v >= lo && v < hi) atomicAdd(&h[v - lo], 1);
    }
    __syncthreads();
    for (int i = t; i < RB; i += 256) {
        int v = h[i];
        if (v && lo + i < N_NODES) atomicAdd(&cnt_src[lo + i], v);  // coalesced
    }
}

// ---------------------------------------------------------------------------
// per-chunk coarse histogram over dst buckets -> cnt2d[b][c]
__global__ void bucket_hist_kernel(const int* __restrict__ dst, int* __restrict__ cnt2d) {
    __shared__ int h[NB];
    int c = blockIdx.x, t = threadIdx.x;
    for (int i = t; i < NB; i += 256) h[i] = 0;
    __syncthreads();
    int base = c * CHUNK;
    int lim = base + CHUNK; if (lim > N_EDGES) lim = N_EDGES;
    for (int e = base + t; e < lim; e += 256) atomicAdd(&h[dst[e] >> 6], 1);
    __syncthreads();
    for (int i = t; i < NB; i += 256) cnt2d[i * NCH + c] = h[i];
}

// --- 3-phase exclusive scan of cnt2d (TOT elements), in place --------------
__global__ void scanA_kernel(int* __restrict__ a, int* __restrict__ bsum) {
    __shared__ int tmp[256];
    int t = threadIdx.x, gid = blockIdx.x * 256 + t;
    int v = (gid < TOT) ? a[gid] : 0;
    tmp[t] = v; __syncthreads();
    for (int off = 1; off < 256; off <<= 1) {
        int u = (t >= off) ? tmp[t - off] : 0;
        __syncthreads();
        tmp[t] += u;
        __syncthreads();
    }
    if (gid < TOT) a[gid] = tmp[t] - v;
    if (t == 255) bsum[blockIdx.x] = tmp[255];
}

__global__ void scanB_kernel(int* __restrict__ bsum) {
    __shared__ int tmp[1024];
    int t = threadIdx.x;
    int v = (t < SCAN_BLKS) ? bsum[t] : 0;
    tmp[t] = v; __syncthreads();
    for (int off = 1; off < 1024; off <<= 1) {
        int u = (t >= off) ? tmp[t - off] : 0;
        __syncthreads();
        tmp[t] += u;
        __syncthreads();
    }
    if (t < SCAN_BLKS) bsum[t] = tmp[t] - v;
}

__global__ void scanC_kernel(int* __restrict__ a, const int* __restrict__ bsum) {
    int gid = blockIdx.x * 256 + threadIdx.x;
    if (gid < TOT) a[gid] += bsum[gid >> 8];
}

// ---------------------------------------------------------------------------
// scatter edges into bucket order; cursors in LDS (bases from scan).
// packed = (dst&63)<<16 | src   (src < 65536)
__global__ void bucket_scatter_kernel(const int* __restrict__ src, const int* __restrict__ dst,
                                      const int* __restrict__ cnt2d, uint32_t* __restrict__ packed) {
    __shared__ int cur[NB];
    int c = blockIdx.x, t = threadIdx.x;
    for (int i = t; i < NB; i += 256) cur[i] = cnt2d[i * NCH + c];
    __syncthreads();
    int base = c * CHUNK;
    int lim = base + CHUNK; if (lim > N_EDGES) lim = N_EDGES;
    for (int e = base + t; e < lim; e += 256) {
        int d = dst[e];
        int slot = atomicAdd(&cur[d >> 6], 1);
        packed[slot] = ((uint32_t)(d & 63) << 16) | (uint32_t)src[e];
    }
}

// ---------------------------------------------------------------------------
// within-bucket counting sort -> per-node CSR. 2-pass over the bucket's
// packed edges (no LDS capacity limit), LDS cursors. Also emits ndst.
__global__ void sort_bucket_kernel(const uint32_t* __restrict__ packed,
                                   const int* __restrict__ cnt2d,
                                   int* __restrict__ sorted_src,
                                   int* __restrict__ node_offs,
                                   float* __restrict__ ndst) {
    __shared__ int hist[64], offs[64], cur[64];
    int b = blockIdx.x, t = threadIdx.x;
    if (t < 64) hist[t] = 0;
    __syncthreads();
    int start = cnt2d[b * NCH];
    int end = (b == NB - 1) ? N_EDGES : cnt2d[(b + 1) * NCH];
    for (int e = start + t; e < end; e += 256) atomicAdd(&hist[packed[e] >> 16], 1);
    __syncthreads();
    if (t == 0) {
        int acc = 0;
        #pragma unroll
        for (int k = 0; k < 64; ++k) { offs[k] = acc; acc += hist[k]; }
    }
    __syncthreads();
    if (t < 64) {
        cur[t] = offs[t];
        int node = b * 64 + t;
        if (node < N_NODES) {
            node_offs[node] = start + offs[t];
            ndst[node] = 1.0f / sqrtf(fmaxf((float)hist[t], 1.0f));
        }
    }
    if (b == 0 && t == 0) node_offs[N_NODES] = N_EDGES;
    __syncthreads();
    for (int e = start + t; e < end; e += 256) {
        uint32_t pk = packed[e];
        int slot = start + atomicAdd(&cur[pk >> 16], 1);
        sorted_src[slot] = (int)(pk & 0xFFFF);
    }
}

// ---------------------------------------------------------------------------
// y1 = (x @ W1) * nsrc ; nsrc computed from cnt_src.
// lane = FEATURE, wave = 16 rows. W1 column slice in VGPRs (coalesced,
// one-time); x rows wave-uniform via readfirstlane -> scalar s_loads;
// y1 stores 64 consecutive floats -> fully coalesced (kills the 4.5x
// write amplification of the lane=row version). k ascending -> bit-identical.
__global__ __launch_bounds__(256) void gemm1_kernel(
        const float* __restrict__ x, const float* __restrict__ W1,
        const int* __restrict__ cnt_src, float* __restrict__ nsrc,
        float* __restrict__ y1) {
    int lane = threadIdx.x & 63;
    int wid = __builtin_amdgcn_readfirstlane((blockIdx.x * blockDim.x + threadIdx.x) >> 6);
    int rbase = wid * 16;
    if (rbase >= N_NODES) return;

    float w[IN_F];                       // W1[k][lane], k = 0..127
    #pragma unroll
    for (int k = 0; k < IN_F; ++k) w[k] = W1[(size_t)k * HID + lane];

    int rlim = N_NODES - rbase;
    #pragma unroll 1
    for (int r = 0; r < 16; ++r) {
        if (r >= rlim) break;
        int row = rbase + r;             // wave-uniform
        const float* xr = x + (size_t)row * IN_F;
        float acc = 0.0f;
        #pragma unroll
        for (int k = 0; k < IN_F; ++k) acc = fmaf(xr[k], w[k], acc);
        float nn = 1.0f / sqrtf(fmaxf((float)cnt_src[row], 1.0f));
        if (lane == 0) nsrc[row] = nn;
        y1[(size_t)row * HID + lane] = acc * nn;
    }
}

// ---------------------------------------------------------------------------
// Layer-1 tail: wave per node, lane = feature, register accumulation.
// agg = sum y1[src]; h = relu(agg*ndst + b1)*drop; s = (h . W2) * nsrc
__global__ void gather1_kernel(const int* __restrict__ node_offs, const int* __restrict__ sorted_src,
                               const float* __restrict__ y1, const float* __restrict__ ndst,
                               const float* __restrict__ nsrc, const float* __restrict__ b1,
                               const float* __restrict__ drop, const float* __restrict__ W2,
                               float* __restrict__ s_out) {
    int lane = threadIdx.x & 63;
    int i = blockIdx.x * (blockDim.x >> 6) + (threadIdx.x >> 6);
    if (i >= N_NODES) return;

    int start = node_offs[i], end = node_offs[i + 1];
    float a0 = 0.0f, a1 = 0.0f, a2 = 0.0f, a3 = 0.0f;
    int j = start;
    for (; j + 4 <= end; j += 4) {
        int s0 = sorted_src[j + 0], s1 = sorted_src[j + 1];
        int s2 = sorted_src[j + 2], s3 = sorted_src[j + 3];
        a0 += y1[(size_t)s0 * HID + lane];
        a1 += y1[(size_t)s1 * HID + lane];
        a2 += y1[(size_t)s2 * HID + lane];
        a3 += y1[(size_t)s3 * HID + lane];
    }
    for (; j < end; ++j) a0 += y1[(size_t)sorted_src[j] * HID + lane];
    float acc = (a0 + a1) + (a2 + a3);

    float a = fmaxf(acc * ndst[i] + b1[lane], 0.0f) * drop[(size_t)i * HID + lane];
    float c = a * W2[lane];
    #pragma unroll
    for (int m = 32; m >= 1; m >>= 1) c += __shfl_xor(c, m, 64);
    if (lane == 0) s_out[i] = c * nsrc[i];
}

// Layer-2: wave per node, lane per edge, fused sigmoid.
__global__ void gather2_kernel(const int* __restrict__ node_offs, const int* __restrict__ sorted_src,
                               const float* __restrict__ s_arr, const float* __restrict__ ndst,
                               const float* __restrict__ b2, float* __restrict__ out) {
    int lane = threadIdx.x & 63;
    int i = blockIdx.x * (blockDim.x >> 6) + (threadIdx.x >> 6);
    if (i >= N_NODES) return;

    int start = node_offs[i], end = node_offs[i + 1];
    float c = 0.0f;
    for (int j = start + lane; j < end; j += 64) c += s_arr[sorted_src[j]];
    #pragma unroll
    for (int m = 32; m >= 1; m >>= 1) c += __shfl_xor(c, m, 64);
    if (lane == 0) {
        float v = c * ndst[i] + b2[0];
        out[i] = 1.0f / (1.0f + expf(-v));
    }
}

// ---------------------------------------------------------------------------
extern "C" void kernel_launch(void* const* d_in, const int* in_sizes, int n_in,
                              void* d_out, int out_size, void* d_ws, size_t ws_size,
                              hipStream_t stream) {
    const float* x    = (const float*)d_in[0];
    const float* W1   = (const float*)d_in[1];
    const float* b1   = (const float*)d_in[2];
    const float* W2   = (const float*)d_in[3];
    const float* b2   = (const float*)d_in[4];
    const int*   src  = (const int*)d_in[5];
    const int*   dst  = (const int*)d_in[6];
    const float* drop = (const float*)d_in[7];
    float* out = (float*)d_out;

    // workspace (~21 MB)
    float*    y1         = (float*)d_ws;                              // 64N
    uint32_t* packed     = (uint32_t*)(y1 + (size_t)HID * N_NODES);   // E
    int*      sorted_src = (int*)(packed + N_EDGES);                  // E
    int*      cnt2d      = sorted_src + N_EDGES;                      // TOT
    int*      bsum       = cnt2d + TOT;                               // 1024
    int*      cnt_src    = bsum + 1024;                               // N (zeroed)
    int*      node_offs  = cnt_src + N_NODES;                         // N+1
    float*    nsrc       = (float*)(node_offs + N_NODES + 1);         // N
    float*    ndst       = nsrc + N_NODES;                            // N
    float*    s_arr      = ndst + N_NODES;                            // N

    hipMemsetAsync(cnt_src, 0, (size_t)N_NODES * sizeof(int), stream);

    hist_src_kernel      <<<NR * HP, 256, 0, stream>>>(src, cnt_src);
    bucket_hist_kernel   <<<NCH, 256, 0, stream>>>(dst, cnt2d);
    scanA_kernel         <<<SCAN_BLKS, 256, 0, stream>>>(cnt2d, bsum);
    scanB_kernel         <<<1, 1024, 0, stream>>>(bsum);
    scanC_kernel         <<<SCAN_BLKS, 256, 0, stream>>>(cnt2d, bsum);
    bucket_scatter_kernel<<<NCH, 256, 0, stream>>>(src, dst, cnt2d, packed);
    sort_bucket_kernel   <<<NB, 256, 0, stream>>>(packed, cnt2d, sorted_src, node_offs, ndst);
    gemm1_kernel         <<<(3125 + 3) / 4, 256, 0, stream>>>(x, W1, cnt_src, nsrc, y1);
    gather1_kernel       <<<(N_NODES + 3) / 4, 256, 0, stream>>>(node_offs, sorted_src, y1, ndst, nsrc, b1, drop, W2, s_arr);
    gather2_kernel       <<<(N_NODES + 3) / 4, 256, 0, stream>>>(node_offs, sorted_src, s_arr, ndst, b2, out);
}

// Round 11
// 278.077 us; speedup vs baseline: 1.3618x; 1.3618x over previous
//
#include <hip/hip_runtime.h>
#include <math.h>
#include <stdint.h>

#define N_NODES 50000
#define N_EDGES 800000
#define IN_F 128
#define HID 64

#define NB    782                        // dst buckets of 64 nodes
#define CHUNK 4096
#define NCH   ((N_EDGES + CHUNK - 1) / CHUNK)   // 196
#define TOT   (NB * NCH)                 // 153272
#define SCAN_BLKS ((TOT + 255) / 256)    // 599  (< 1024 for scanB)

#define RB 16000                         // hist bins per range (62.5KB LDS)
#define NR 4                             // 4*16000 >= 50000
#define HP 64                            // slices per range -> 256 blocks

// ---------------------------------------------------------------------------
// src out-degree histogram: LDS-staged, coalesced global flush.
__global__ void hist_src_kernel(const int* __restrict__ src, int* __restrict__ cnt_src) {
    __shared__ int h[RB];
    int r = blockIdx.x / HP;             // range
    int p = blockIdx.x % HP;             // slice
    int t = threadIdx.x;
    for (int i = t; i < RB; i += 256) h[i] = 0;
    __syncthreads();
    int lo = r * RB, hi = lo + RB;
    int base = p * (N_EDGES / HP), lim = base + (N_EDGES / HP);   // 12500 exact
    for (int e = base + t; e < lim; e += 256) {
        int v = src[e];
        if (v >= lo && v < hi) atomicAdd(&h[v - lo], 1);
    }
    __syncthreads();
    for (int i = t; i < RB; i += 256) {
        int v = h[i];
        if (v && lo + i < N_NODES) atomicAdd(&cnt_src[lo + i], v);  // coalesced
    }
}

// ---------------------------------------------------------------------------
// per-chunk coarse histogram over dst buckets -> cnt2d[b][c]
__global__ void bucket_hist_kernel(const int* __restrict__ dst, int* __restrict__ cnt2d) {
    __shared__ int h[NB];
    int c = blockIdx.x, t = threadIdx.x;
    for (int i = t; i < NB; i += 256) h[i] = 0;
    __syncthreads();
    int base = c * CHUNK;
    int lim = base + CHUNK; if (lim > N_EDGES) lim = N_EDGES;
    for (int e = base + t; e < lim; e += 256) atomicAdd(&h[dst[e] >> 6], 1);
    __syncthreads();
    for (int i = t; i < NB; i += 256) cnt2d[i * NCH + c] = h[i];
}

// --- 3-phase exclusive scan of cnt2d (TOT elements), in place --------------
__global__ void scanA_kernel(int* __restrict__ a, int* __restrict__ bsum) {
    __shared__ int tmp[256];
    int t = threadIdx.x, gid = blockIdx.x * 256 + t;
    int v = (gid < TOT) ? a[gid] : 0;
    tmp[t] = v; __syncthreads();
    for (int off = 1; off < 256; off <<= 1) {
        int u = (t >= off) ? tmp[t - off] : 0;
        __syncthreads();
        tmp[t] += u;
        __syncthreads();
    }
    if (gid < TOT) a[gid] = tmp[t] - v;
    if (t == 255) bsum[blockIdx.x] = tmp[255];
}

__global__ void scanB_kernel(int* __restrict__ bsum) {
    __shared__ int tmp[1024];
    int t = threadIdx.x;
    int v = (t < SCAN_BLKS) ? bsum[t] : 0;
    tmp[t] = v; __syncthreads();
    for (int off = 1; off < 1024; off <<= 1) {
        int u = (t >= off) ? tmp[t - off] : 0;
        __syncthreads();
        tmp[t] += u;
        __syncthreads();
    }
    if (t < SCAN_BLKS) bsum[t] = tmp[t] - v;
}

__global__ void scanC_kernel(int* __restrict__ a, const int* __restrict__ bsum) {
    int gid = blockIdx.x * 256 + threadIdx.x;
    if (gid < TOT) a[gid] += bsum[gid >> 8];
}

// ---------------------------------------------------------------------------
// scatter edges into bucket order; cursors in LDS (bases from scan).
// packed = (dst&63)<<16 | src   (src < 65536)
__global__ void bucket_scatter_kernel(const int* __restrict__ src, const int* __restrict__ dst,
                                      const int* __restrict__ cnt2d, uint32_t* __restrict__ packed) {
    __shared__ int cur[NB];
    int c = blockIdx.x, t = threadIdx.x;
    for (int i = t; i < NB; i += 256) cur[i] = cnt2d[i * NCH + c];
    __syncthreads();
    int base = c * CHUNK;
    int lim = base + CHUNK; if (lim > N_EDGES) lim = N_EDGES;
    for (int e = base + t; e < lim; e += 256) {
        int d = dst[e];
        int slot = atomicAdd(&cur[d >> 6], 1);
        packed[slot] = ((uint32_t)(d & 63) << 16) | (uint32_t)src[e];
    }
}

// ---------------------------------------------------------------------------
// within-bucket counting sort -> per-node CSR. 2-pass over the bucket's
// packed edges (no LDS capacity limit), LDS cursors. Also emits ndst.
__global__ void sort_bucket_kernel(const uint32_t* __restrict__ packed,
                                   const int* __restrict__ cnt2d,
                                   int* __restrict__ sorted_src,
                                   int* __restrict__ node_offs,
                                   float* __restrict__ ndst) {
    __shared__ int hist[64], offs[64], cur[64];
    int b = blockIdx.x, t = threadIdx.x;
    if (t < 64) hist[t] = 0;
    __syncthreads();
    int start = cnt2d[b * NCH];
    int end = (b == NB - 1) ? N_EDGES : cnt2d[(b + 1) * NCH];
    for (int e = start + t; e < end; e += 256) atomicAdd(&hist[packed[e] >> 16], 1);
    __syncthreads();
    if (t == 0) {
        int acc = 0;
        #pragma unroll
        for (int k = 0; k < 64; ++k) { offs[k] = acc; acc += hist[k]; }
    }
    __syncthreads();
    if (t < 64) {
        cur[t] = offs[t];
        int node = b * 64 + t;
        if (node < N_NODES) {
            node_offs[node] = start + offs[t];
            ndst[node] = 1.0f / sqrtf(fmaxf((float)hist[t], 1.0f));
        }
    }
    if (b == 0 && t == 0) node_offs[N_NODES] = N_EDGES;
    __syncthreads();
    for (int e = start + t; e < end; e += 256) {
        uint32_t pk = packed[e];
        int slot = start + atomicAdd(&cur[pk >> 16], 1);
        sorted_src[slot] = (int)(pk & 0xFFFF);
    }
}

// ---------------------------------------------------------------------------
// y1 = (x @ W1) * nsrc ; nsrc computed from cnt_src.
// lane = row (64 rows/wave), wave = 16 features (fq = threadIdx>>6 selects
// the feature quarter). R8's proven body (xk in VGPRs, wave-uniform scalar
// W1 loads, independent acc chains) but 4x the waves (3128) and 64B
// contiguous stores per lane (kills the 4.5x write amplification).
// k ascends 0..127 per feature -> bit-identical summation order.
__global__ __launch_bounds__(256) void gemm1_kernel(
        const float* __restrict__ x, const float* __restrict__ W1,
        const int* __restrict__ cnt_src, float* __restrict__ nsrc,
        float* __restrict__ y1) {
    int lane = threadIdx.x & 63;         // row within group
    int fq   = threadIdx.x >> 6;         // feature quarter 0..3 (wave-uniform)
    int row  = blockIdx.x * 64 + lane;
    if (row >= N_NODES) return;

    float acc[16];
    #pragma unroll
    for (int f = 0; f < 16; ++f) acc[f] = 0.0f;

    #pragma unroll 1
    for (int kc = 0; kc < 4; ++kc) {              // 4 chunks of 32 k's
        float xk[32];
        const float4* xp = reinterpret_cast<const float4*>(x + (size_t)row * IN_F + kc * 32);
        #pragma unroll
        for (int q = 0; q < 8; ++q) {
            float4 tq = xp[q];
            xk[4 * q + 0] = tq.x; xk[4 * q + 1] = tq.y;
            xk[4 * q + 2] = tq.z; xk[4 * q + 3] = tq.w;
        }
        #pragma unroll
        for (int k = 0; k < 32; ++k) {
            const float* wr = W1 + (size_t)(kc * 32 + k) * HID + fq * 16;  // uniform -> s_load
            #pragma unroll
            for (int f = 0; f < 16; ++f) acc[f] = fmaf(xk[k], wr[f], acc[f]);
        }
    }
    float nn = 1.0f / sqrtf(fmaxf((float)cnt_src[row], 1.0f));
    if (fq == 0) nsrc[row] = nn;
    float4* yp = reinterpret_cast<float4*>(y1 + (size_t)row * HID + fq * 16);
    #pragma unroll
    for (int q = 0; q < 4; ++q)
        yp[q] = make_float4(acc[4 * q] * nn, acc[4 * q + 1] * nn,
                            acc[4 * q + 2] * nn, acc[4 * q + 3] * nn);
}

// ---------------------------------------------------------------------------
// Layer-1 tail: wave per node, lane = feature, register accumulation.
// agg = sum y1[src]; h = relu(agg*ndst + b1)*drop; s = (h . W2) * nsrc
__global__ void gather1_kernel(const int* __restrict__ node_offs, const int* __restrict__ sorted_src,
                               const float* __restrict__ y1, const float* __restrict__ ndst,
                               const float* __restrict__ nsrc, const float* __restrict__ b1,
                               const float* __restrict__ drop, const float* __restrict__ W2,
                               float* __restrict__ s_out) {
    int lane = threadIdx.x & 63;
    int i = blockIdx.x * (blockDim.x >> 6) + (threadIdx.x >> 6);
    if (i >= N_NODES) return;

    int start = node_offs[i], end = node_offs[i + 1];
    float a0 = 0.0f, a1 = 0.0f, a2 = 0.0f, a3 = 0.0f;
    int j = start;
    for (; j + 4 <= end; j += 4) {
        int s0 = sorted_src[j + 0], s1 = sorted_src[j + 1];
        int s2 = sorted_src[j + 2], s3 = sorted_src[j + 3];
        a0 += y1[(size_t)s0 * HID + lane];
        a1 += y1[(size_t)s1 * HID + lane];
        a2 += y1[(size_t)s2 * HID + lane];
        a3 += y1[(size_t)s3 * HID + lane];
    }
    for (; j < end; ++j) a0 += y1[(size_t)sorted_src[j] * HID + lane];
    float acc = (a0 + a1) + (a2 + a3);

    float a = fmaxf(acc * ndst[i] + b1[lane], 0.0f) * drop[(size_t)i * HID + lane];
    float c = a * W2[lane];
    #pragma unroll
    for (int m = 32; m >= 1; m >>= 1) c += __shfl_xor(c, m, 64);
    if (lane == 0) s_out[i] = c * nsrc[i];
}

// Layer-2: wave per node, lane per edge, fused sigmoid.
__global__ void gather2_kernel(const int* __restrict__ node_offs, const int* __restrict__ sorted_src,
                               const float* __restrict__ s_arr, const float* __restrict__ ndst,
                               const float* __restrict__ b2, float* __restrict__ out) {
    int lane = threadIdx.x & 63;
    int i = blockIdx.x * (blockDim.x >> 6) + (threadIdx.x >> 6);
    if (i >= N_NODES) return;

    int start = node_offs[i], end = node_offs[i + 1];
    float c = 0.0f;
    for (int j = start + lane; j < end; j += 64) c += s_arr[sorted_src[j]];
    #pragma unroll
    for (int m = 32; m >= 1; m >>= 1) c += __shfl_xor(c, m, 64);
    if (lane == 0) {
        float v = c * ndst[i] + b2[0];
        out[i] = 1.0f / (1.0f + expf(-v));
    }
}

// ---------------------------------------------------------------------------
extern "C" void kernel_launch(void* const* d_in, const int* in_sizes, int n_in,
                              void* d_out, int out_size, void* d_ws, size_t ws_size,
                              hipStream_t stream) {
    const float* x    = (const float*)d_in[0];
    const float* W1   = (const float*)d_in[1];
    const float* b1   = (const float*)d_in[2];
    const float* W2   = (const float*)d_in[3];
    const float* b2   = (const float*)d_in[4];
    const int*   src  = (const int*)d_in[5];
    const int*   dst  = (const int*)d_in[6];
    const float* drop = (const float*)d_in[7];
    float* out = (float*)d_out;

    // workspace (~21 MB)
    float*    y1         = (float*)d_ws;                              // 64N
    uint32_t* packed     = (uint32_t*)(y1 + (size_t)HID * N_NODES);   // E
    int*      sorted_src = (int*)(packed + N_EDGES);                  // E
    int*      cnt2d      = sorted_src + N_EDGES;                      // TOT
    int*      bsum       = cnt2d + TOT;                               // 1024
    int*      cnt_src    = bsum + 1024;                               // N (zeroed)
    int*      node_offs  = cnt_src + N_NODES;                         // N+1
    float*    nsrc       = (float*)(node_offs + N_NODES + 1);         // N
    float*    ndst       = nsrc + N_NODES;                            // N
    float*    s_arr      = ndst + N_NODES;                            // N

    hipMemsetAsync(cnt_src, 0, (size_t)N_NODES * sizeof(int), stream);

    hist_src_kernel      <<<NR * HP, 256, 0, stream>>>(src, cnt_src);
    bucket_hist_kernel   <<<NCH, 256, 0, stream>>>(dst, cnt2d);
    scanA_kernel         <<<SCAN_BLKS, 256, 0, stream>>>(cnt2d, bsum);
    scanB_kernel         <<<1, 1024, 0, stream>>>(bsum);
    scanC_kernel         <<<SCAN_BLKS, 256, 0, stream>>>(cnt2d, bsum);
    bucket_scatter_kernel<<<NCH, 256, 0, stream>>>(src, dst, cnt2d, packed);
    sort_bucket_kernel   <<<NB, 256, 0, stream>>>(packed, cnt2d, sorted_src, node_offs, ndst);
    gemm1_kernel         <<<NB, 256, 0, stream>>>(x, W1, cnt_src, nsrc, y1);
    gather1_kernel       <<<(N_NODES + 3) / 4, 256, 0, stream>>>(node_offs, sorted_src, y1, ndst, nsrc, b1, drop, W2, s_arr);
    gather2_kernel       <<<(N_NODES + 3) / 4, 256, 0, stream>>>(node_offs, sorted_src, s_arr, ndst, b2, out);
}

// Round 16
// 239.102 us; speedup vs baseline: 1.5838x; 1.1630x over previous
//
#include <hip/hip_runtime.h>
#include <math.h>
#include <stdint.h>

#define N_NODES 50000
#define N_EDGES 800000
#define IN_F 128
#define HID 64

#define NB    782                        // dst buckets of 64 nodes
#define CHUNK 4096
#define NCH   ((N_EDGES + CHUNK - 1) / CHUNK)   // 196
#define TOT   (NB * NCH)                 // 153272
#define SCAN_BLKS ((TOT + 255) / 256)    // 599  (< 1024 for scanB)

#define RB 16000                         // hist bins per range (62.5KB LDS)
#define NR 4                             // 4*16000 >= 50000
#define HP 64                            // slices per range -> 256 blocks

// ---------------------------------------------------------------------------
// src out-degree histogram: LDS-staged, coalesced global flush.
__global__ void hist_src_kernel(const int* __restrict__ src, int* __restrict__ cnt_src) {
    __shared__ int h[RB];
    int r = blockIdx.x / HP;             // range
    int p = blockIdx.x % HP;             // slice
    int t = threadIdx.x;
    for (int i = t; i < RB; i += 256) h[i] = 0;
    __syncthreads();
    int lo = r * RB, hi = lo + RB;
    int base = p * (N_EDGES / HP), lim = base + (N_EDGES / HP);   // 12500 exact
    for (int e = base + t; e < lim; e += 256) {
        int v = src[e];
        if (v >= lo && v < hi) atomicAdd(&h[v - lo], 1);
    }
    __syncthreads();
    for (int i = t; i < RB; i += 256) {
        int v = h[i];
        if (v && lo + i < N_NODES) atomicAdd(&cnt_src[lo + i], v);  // coalesced
    }
}

// ---------------------------------------------------------------------------
// per-chunk coarse histogram over dst buckets -> cnt2d[b][c]
__global__ void bucket_hist_kernel(const int* __restrict__ dst, int* __restrict__ cnt2d) {
    __shared__ int h[NB];
    int c = blockIdx.x, t = threadIdx.x;
    for (int i = t; i < NB; i += 256) h[i] = 0;
    __syncthreads();
    int base = c * CHUNK;
    int lim = base + CHUNK; if (lim > N_EDGES) lim = N_EDGES;
    for (int e = base + t; e < lim; e += 256) atomicAdd(&h[dst[e] >> 6], 1);
    __syncthreads();
    for (int i = t; i < NB; i += 256) cnt2d[i * NCH + c] = h[i];
}

// --- scan of cnt2d: A (per-block excl) + B (block offsets). The final add
// of bsum[idx>>8] is folded into the consumers (scanC eliminated). ----------
__global__ void scanA_kernel(int* __restrict__ a, int* __restrict__ bsum) {
    __shared__ int tmp[256];
    int t = threadIdx.x, gid = blockIdx.x * 256 + t;
    int v = (gid < TOT) ? a[gid] : 0;
    tmp[t] = v; __syncthreads();
    for (int off = 1; off < 256; off <<= 1) {
        int u = (t >= off) ? tmp[t - off] : 0;
        __syncthreads();
        tmp[t] += u;
        __syncthreads();
    }
    if (gid < TOT) a[gid] = tmp[t] - v;
    if (t == 255) bsum[blockIdx.x] = tmp[255];
}

__global__ void scanB_kernel(int* __restrict__ bsum) {
    __shared__ int tmp[1024];
    int t = threadIdx.x;
    int v = (t < SCAN_BLKS) ? bsum[t] : 0;
    tmp[t] = v; __syncthreads();
    for (int off = 1; off < 1024; off <<= 1) {
        int u = (t >= off) ? tmp[t - off] : 0;
        __syncthreads();
        tmp[t] += u;
        __syncthreads();
    }
    if (t < SCAN_BLKS) bsum[t] = tmp[t] - v;
}

// ---------------------------------------------------------------------------
// scatter edges into bucket order; cursors in LDS, bases = cnt2d + bsum.
// packed = (dst&63)<<16 | src   (src < 65536)
__global__ void bucket_scatter_kernel(const int* __restrict__ src, const int* __restrict__ dst,
                                      const int* __restrict__ cnt2d, const int* __restrict__ bsum,
                                      uint32_t* __restrict__ packed) {
    __shared__ int cur[NB];
    int c = blockIdx.x, t = threadIdx.x;
    for (int i = t; i < NB; i += 256) {
        int idx = i * NCH + c;
        cur[i] = cnt2d[idx] + bsum[idx >> 8];
    }
    __syncthreads();
    int base = c * CHUNK;
    int lim = base + CHUNK; if (lim > N_EDGES) lim = N_EDGES;
    for (int e = base + t; e < lim; e += 256) {
        int d = dst[e];
        int slot = atomicAdd(&cur[d >> 6], 1);
        packed[slot] = ((uint32_t)(d & 63) << 16) | (uint32_t)src[e];
    }
}

// ---------------------------------------------------------------------------
// within-bucket counting sort -> per-node CSR. 2-pass over the bucket's
// packed edges, LDS cursors. Also emits ndst. Bucket bounds = cnt2d + bsum.
__global__ void sort_bucket_kernel(const uint32_t* __restrict__ packed,
                                   const int* __restrict__ cnt2d,
                                   const int* __restrict__ bsum,
                                   int* __restrict__ sorted_src,
                                   int* __restrict__ node_offs,
                                   float* __restrict__ ndst) {
    __shared__ int hist[64], offs[64], cur[64];
    int b = blockIdx.x, t = threadIdx.x;
    if (t < 64) hist[t] = 0;
    __syncthreads();
    int i0 = b * NCH;
    int start = cnt2d[i0] + bsum[i0 >> 8];
    int end;
    if (b == NB - 1) end = N_EDGES;
    else { int i1 = (b + 1) * NCH; end = cnt2d[i1] + bsum[i1 >> 8]; }
    for (int e = start + t; e < end; e += 256) atomicAdd(&hist[packed[e] >> 16], 1);
    __syncthreads();
    if (t == 0) {
        int acc = 0;
        #pragma unroll
        for (int k = 0; k < 64; ++k) { offs[k] = acc; acc += hist[k]; }
    }
    __syncthreads();
    if (t < 64) {
        cur[t] = offs[t];
        int node = b * 64 + t;
        if (node < N_NODES) {
            node_offs[node] = start + offs[t];
            ndst[node] = 1.0f / sqrtf(fmaxf((float)hist[t], 1.0f));
        }
    }
    if (b == 0 && t == 0) node_offs[N_NODES] = N_EDGES;
    __syncthreads();
    for (int e = start + t; e < end; e += 256) {
        uint32_t pk = packed[e];
        int slot = start + atomicAdd(&cur[pk >> 16], 1);
        sorted_src[slot] = (int)(pk & 0xFFFF);
    }
}

// ---------------------------------------------------------------------------
// y1 = (x @ W1) * nsrc ; nsrc from cnt_src.
// R8's proven body: thread = row, 64 independent acc chains, xk[32] via
// float4, wave-uniform scalar W1 loads. NEW: stores go through a per-wave
// LDS transpose tile (padded +1 -> conflict-free) so each global store is
// a 256B coalesced row -- removes R8's 4.5x write amplification (57->13MB).
// k ascends 0..127 -> summation order identical to R8.
__global__ __launch_bounds__(256) void gemm1_kernel(
        const float* __restrict__ x, const float* __restrict__ W1,
        const int* __restrict__ cnt_src, float* __restrict__ nsrc,
        float* __restrict__ y1) {
    __shared__ float tile[4][64][65];
    int lane = threadIdx.x & 63;
    int w    = threadIdx.x >> 6;
    int row  = blockIdx.x * 256 + threadIdx.x;          // thread = row
    int wavebase = blockIdx.x * 256 + w * 64;

    if (row < N_NODES) {
        float acc[HID];
        #pragma unroll
        for (int f = 0; f < HID; ++f) acc[f] = 0.0f;

        #pragma unroll 1
        for (int kc = 0; kc < 4; ++kc) {                // 4 chunks of 32 k's
            float xk[32];
            const float4* xp = reinterpret_cast<const float4*>(x + (size_t)row * IN_F + kc * 32);
            #pragma unroll
            for (int q = 0; q < 8; ++q) {
                float4 tq = xp[q];
                xk[4 * q + 0] = tq.x; xk[4 * q + 1] = tq.y;
                xk[4 * q + 2] = tq.z; xk[4 * q + 3] = tq.w;
            }
            #pragma unroll
            for (int k = 0; k < 32; ++k) {
                const float* wr = W1 + (size_t)(kc * 32 + k) * HID;  // uniform -> s_load
                #pragma unroll
                for (int f = 0; f < HID; ++f) acc[f] = fmaf(xk[k], wr[f], acc[f]);
            }
        }
        float nn = 1.0f / sqrtf(fmaxf((float)cnt_src[row], 1.0f));
        nsrc[row] = nn;
        #pragma unroll
        for (int f = 0; f < HID; ++f) tile[w][lane][f] = acc[f] * nn;
    }
    __syncthreads();   // uniform; orders LDS writes before transposed reads

    int rmax = N_NODES - wavebase;
    if (rmax > 64) rmax = 64;
    for (int r = 0; r < rmax; ++r)                      // lane = feature
        y1[(size_t)(wavebase + r) * HID + lane] = tile[w][r][lane];
}

// ---------------------------------------------------------------------------
// Layer-1 tail: wave per node, lane = feature, register accumulation.
// agg = sum y1[src]; h = relu(agg*ndst + b1)*drop; s = (h . W2) * nsrc
__global__ void gather1_kernel(const int* __restrict__ node_offs, const int* __restrict__ sorted_src,
                               const float* __restrict__ y1, const float* __restrict__ ndst,
                               const float* __restrict__ nsrc, const float* __restrict__ b1,
                               const float* __restrict__ drop, const float* __restrict__ W2,
                               float* __restrict__ s_out) {
    int lane = threadIdx.x & 63;
    int i = blockIdx.x * (blockDim.x >> 6) + (threadIdx.x >> 6);
    if (i >= N_NODES) return;

    int start = node_offs[i], end = node_offs[i + 1];
    float a0 = 0.0f, a1 = 0.0f, a2 = 0.0f, a3 = 0.0f;
    int j = start;
    for (; j + 4 <= end; j += 4) {
        int s0 = sorted_src[j + 0], s1 = sorted_src[j + 1];
        int s2 = sorted_src[j + 2], s3 = sorted_src[j + 3];
        a0 += y1[(size_t)s0 * HID + lane];
        a1 += y1[(size_t)s1 * HID + lane];
        a2 += y1[(size_t)s2 * HID + lane];
        a3 += y1[(size_t)s3 * HID + lane];
    }
    for (; j < end; ++j) a0 += y1[(size_t)sorted_src[j] * HID + lane];
    float acc = (a0 + a1) + (a2 + a3);

    float a = fmaxf(acc * ndst[i] + b1[lane], 0.0f) * drop[(size_t)i * HID + lane];
    float c = a * W2[lane];
    #pragma unroll
    for (int m = 32; m >= 1; m >>= 1) c += __shfl_xor(c, m, 64);
    if (lane == 0) s_out[i] = c * nsrc[i];
}

// Layer-2: wave per node, lane per edge, fused sigmoid.
__global__ void gather2_kernel(const int* __restrict__ node_offs, const int* __restrict__ sorted_src,
                               const float* __restrict__ s_arr, const float* __restrict__ ndst,
                               const float* __restrict__ b2, float* __restrict__ out) {
    int lane = threadIdx.x & 63;
    int i = blockIdx.x * (blockDim.x >> 6) + (threadIdx.x >> 6);
    if (i >= N_NODES) return;

    int start = node_offs[i], end = node_offs[i + 1];
    float c = 0.0f;
    for (int j = start + lane; j < end; j += 64) c += s_arr[sorted_src[j]];
    #pragma unroll
    for (int m = 32; m >= 1; m >>= 1) c += __shfl_xor(c, m, 64);
    if (lane == 0) {
        float v = c * ndst[i] + b2[0];
        out[i] = 1.0f / (1.0f + expf(-v));
    }
}

// ---------------------------------------------------------------------------
extern "C" void kernel_launch(void* const* d_in, const int* in_sizes, int n_in,
                              void* d_out, int out_size, void* d_ws, size_t ws_size,
                              hipStream_t stream) {
    const float* x    = (const float*)d_in[0];
    const float* W1   = (const float*)d_in[1];
    const float* b1   = (const float*)d_in[2];
    const float* W2   = (const float*)d_in[3];
    const float* b2   = (const float*)d_in[4];
    const int*   src  = (const int*)d_in[5];
    const int*   dst  = (const int*)d_in[6];
    const float* drop = (const float*)d_in[7];
    float* out = (float*)d_out;

    // workspace (~21 MB)
    float*    y1         = (float*)d_ws;                              // 64N
    uint32_t* packed     = (uint32_t*)(y1 + (size_t)HID * N_NODES);   // E
    int*      sorted_src = (int*)(packed + N_EDGES);                  // E
    int*      cnt2d      = sorted_src + N_EDGES;                      // TOT
    int*      bsum       = cnt2d + TOT;                               // 1024
    int*      cnt_src    = bsum + 1024;                               // N (zeroed)
    int*      node_offs  = cnt_src + N_NODES;                         // N+1
    float*    nsrc       = (float*)(node_offs + N_NODES + 1);         // N
    float*    ndst       = nsrc + N_NODES;                            // N
    float*    s_arr      = ndst + N_NODES;                            // N

    hipMemsetAsync(cnt_src, 0, (size_t)N_NODES * sizeof(int), stream);

    hist_src_kernel      <<<NR * HP, 256, 0, stream>>>(src, cnt_src);
    bucket_hist_kernel   <<<NCH, 256, 0, stream>>>(dst, cnt2d);
    scanA_kernel         <<<SCAN_BLKS, 256, 0, stream>>>(cnt2d, bsum);
    scanB_kernel         <<<1, 1024, 0, stream>>>(bsum);
    bucket_scatter_kernel<<<NCH, 256, 0, stream>>>(src, dst, cnt2d, bsum, packed);
    sort_bucket_kernel   <<<NB, 256, 0, stream>>>(packed, cnt2d, bsum, sorted_src, node_offs, ndst);
    gemm1_kernel         <<<(N_NODES + 255) / 256, 256, 0, stream>>>(x, W1, cnt_src, nsrc, y1);
    gather1_kernel       <<<(N_NODES + 3) / 4, 256, 0, stream>>>(node_offs, sorted_src, y1, ndst, nsrc, b1, drop, W2, s_arr);
    gather2_kernel       <<<(N_NODES + 3) / 4, 256, 0, stream>>>(node_offs, sorted_src, s_arr, ndst, b2, out);
}